// Round 12
// baseline (648.571 us; speedup 1.0000x reference)
//
#include <hip/hip_runtime.h>
#include <hip/hip_cooperative_groups.h>

namespace cg = cooperative_groups;

// BrickVectorEdgeModel on MI355X (gfx950).
// R12: single cooperative mega-kernel (prep -> node L1/L2/L3 -> edge) to
// kill ~80us of launch/drain gaps between 5 small dependent dispatches.
// Edge phase = EXACT R7 body (padded LDSW=520, MT9/NT4, wF dbuf + eF
// rotating -- the only proven no-spill shape, 157us), looped 4 tiles/block.
// 256 blocks x 512 thr, 159KB LDS -> 1 block/CU, co-residency guaranteed.

typedef short  short8  __attribute__((ext_vector_type(8)));
typedef short  short4v __attribute__((ext_vector_type(4)));
typedef float  f32x4   __attribute__((ext_vector_type(4)));

#define LDSW 520   // padded LDS row stride (bf16 elems)

__device__ inline unsigned short f2bf(float x) {
  unsigned u = __float_as_uint(x);
  unsigned r = (u + 0x7FFFu + ((u >> 16) & 1u)) >> 16;  // RNE
  return (unsigned short)r;
}

template <int MT, int NT>
__device__ inline void zero_acc(f32x4 (&acc)[MT][NT]) {
#pragma unroll
  for (int mt = 0; mt < MT; ++mt)
#pragma unroll
    for (int nt = 0; nt < NT; ++nt) {
      f32x4 z = {0.f, 0.f, 0.f, 0.f};
      acc[mt][nt] = z;
    }
}

// R7-exact k-loop. W as MFMA A-operand (m = out-col), E as B-operand
// (n = edge-row). Lane holds out-cols kg*4+r at edge-row mt*16+(lane&15).
// W tiled: contiguous 1KB fragment per (col_tile, kstep).
// wF register double-buffered; eF JIT rotating prefetch (2 live).
template <int MT, int NT>
__device__ inline void gemm_kloop(const short* E, const short* __restrict__ W,
                                  int lane, int nbase, f32x4 (&acc)[MT][NT]) {
  const int mrow = lane & 15, kg = lane >> 4;
  const short* El = E + mrow * LDSW + kg * 8;
  const short* Wl = W + (nbase >> 4) * 8192 + mrow * 32 + kg * 8;
  short8 wF[2][NT];
#pragma unroll
  for (int nt = 0; nt < NT; ++nt) wF[0][nt] = *(const short8*)(Wl + nt * 8192);
#pragma unroll
  for (int ks = 0; ks < 16; ++ks) {
    const int cur = ks & 1, nxt = cur ^ 1;
    if (ks < 15) {
      const int k1 = (ks + 1) * 512;
#pragma unroll
      for (int nt = 0; nt < NT; ++nt)
        wF[nxt][nt] = *(const short8*)(Wl + nt * 8192 + k1);
    }
    const int k0 = ks * 32;
    short8 e0 = *(const short8*)(El + k0);
#pragma unroll
    for (int mt = 0; mt < MT; ++mt) {
      const short8 ecur = e0;
      if (mt < MT - 1) e0 = *(const short8*)(El + (mt + 1) * 16 * LDSW + k0);
#pragma unroll
      for (int nt = 0; nt < NT; ++nt)
        acc[mt][nt] = __builtin_amdgcn_mfma_f32_16x16x32_bf16(
            wF[cur][nt], ecur, acc[mt][nt], 0, 0, 0);
    }
  }
}

// relu(acc + bias[outcol]) -> bf16 -> padded LDS, 8B vector writes.
template <int MT, int NT>
__device__ inline void store_relu_lds(short* E, const float* __restrict__ bias,
                                      int lane, int nbase, f32x4 (&acc)[MT][NT]) {
  const int mrow = lane & 15, kg = lane >> 4;
#pragma unroll
  for (int nt = 0; nt < NT; ++nt) {
    const int oc = nbase + nt * 16 + kg * 4;
    const float4 bs = *(const float4*)(bias + oc);
#pragma unroll
    for (int mt = 0; mt < MT; ++mt) {
      short4v s;
      s.x = (short)f2bf(fmaxf(acc[mt][nt][0] + bs.x, 0.f));
      s.y = (short)f2bf(fmaxf(acc[mt][nt][1] + bs.y, 0.f));
      s.z = (short)f2bf(fmaxf(acc[mt][nt][2] + bs.z, 0.f));
      s.w = (short)f2bf(fmaxf(acc[mt][nt][3] + bs.w, 0.f));
      *(short4v*)&E[(mt * 16 + mrow) * LDSW + oc] = s;
    }
  }
}

// ---- node phase (device fn): 64 rows x 128 cols per block, 8 waves NT=1 ----
// MODE 1: X=bv fp32 -> relu(X@Wa^T + xy-term + ba + bxy) -> bf16 f1
// MODE 2: X=f1 bf16 -> relu(X@Wb^T + bb) -> bf16 f2
// MODE 3: X=f2 bf16 -> X@Wuv^T (1024 cols) -> fp32 u (ct<4) / v (ct>=4)
template <int MODE>
__device__ void node_phase(short* X, float* xyl,
                           const void* Xin, const short* __restrict__ W,
                           const float* bias, const float* xy,
                           const float* Wxy, const float* bxy,
                           void* Yout, float* vout) {
  const int tid = threadIdx.x, lane = tid & 63, wave = tid >> 6;
  const int bid = blockIdx.x;
  const int rt = (MODE == 3) ? (bid >> 3) : (bid >> 2);
  const int ct = (MODE == 3) ? (bid & 7) : (bid & 3);
  const int row0 = rt * 64, c0 = ct * 128;

  if (MODE == 1) {
    const float* bv = (const float*)Xin;
    const int hc = (tid & 127) * 4, m0 = tid >> 7;
    for (int m = m0; m < 64; m += 4) {
      const float4 t = *(const float4*)(bv + (row0 + m) * 512 + hc);
      short4v s;
      s.x = (short)f2bf(t.x); s.y = (short)f2bf(t.y);
      s.z = (short)f2bf(t.z); s.w = (short)f2bf(t.w);
      *(short4v*)&X[m * LDSW + hc] = s;
    }
    if (tid < 128) xyl[tid] = xy[row0 * 2 + tid];
  } else {
    const short* xb = (const short*)Xin;
    const int hc = (tid & 63) * 8, m0 = tid >> 6;
    for (int m = m0; m < 64; m += 8)
      *(short8*)&X[m * LDSW + hc] = *(const short8*)(xb + (row0 + m) * 512 + hc);
  }
  __syncthreads();

  const int nbase = c0 + wave * 16;
  f32x4 acc[4][1];
  zero_acc<4, 1>(acc);
  gemm_kloop<4, 1>(X, W, lane, nbase, acc);

  const int mrow = lane & 15, kg = lane >> 4;
  const int oc = nbase + kg * 4;
  if (MODE == 3) {
    float* u = (float*)Yout;
#pragma unroll
    for (int mt = 0; mt < 4; ++mt) {
      const int row = row0 + mt * 16 + mrow;
      if (oc < 512) *(f32x4*)&u[row * 512 + oc] = acc[mt][0];   // block-uniform
      else          *(f32x4*)&vout[row * 512 + oc - 512] = acc[mt][0];
    }
  } else {
    short* Y = (short*)Yout;
    const float4 bs = *(const float4*)(bias + oc);
    float b2[4] = {0.f, 0.f, 0.f, 0.f}, w0[4], w1[4];
    if (MODE == 1) {
      const float4 t = *(const float4*)(bxy + oc);
      b2[0] = t.x; b2[1] = t.y; b2[2] = t.z; b2[3] = t.w;
#pragma unroll
      for (int r = 0; r < 4; ++r) { w0[r] = Wxy[(oc + r) * 2]; w1[r] = Wxy[(oc + r) * 2 + 1]; }
    }
#pragma unroll
    for (int mt = 0; mt < 4; ++mt) {
      const int row = mt * 16 + mrow;
      short4v s;
#pragma unroll
      for (int r = 0; r < 4; ++r) {
        float xv = acc[mt][0][r] + ((const float*)&bs)[r];
        if (MODE == 1) xv += b2[r] + xyl[row * 2] * w0[r] + xyl[row * 2 + 1] * w1[r];
        ((short*)&s)[r] = (short)f2bf(fmaxf(xv, 0.f));
      }
      *(short4v*)&Y[(row0 + row) * 512 + oc] = s;
    }
  }
}

// ---- edge tile (device fn): R7-exact body, tile index tk (0..1023) ----
__device__ void edge_tile(short* A, float* red, int tk,
                          const float* __restrict__ u, const float* __restrict__ v,
                          const short* __restrict__ Wcb, const short* __restrict__ Wcc,
                          const short* __restrict__ Wout,
                          const float* __restrict__ bca, const float* __restrict__ bcb,
                          const float* __restrict__ bcc, const float* __restrict__ bout,
                          float* __restrict__ out) {
  const int tid = threadIdx.x, lane = tid & 63, wave = tid >> 6;
  const int b = tk >> 8, rem = tk & 255, ip = rem >> 2, jt = rem & 3;
  const float* urow0 = u + (b * 192 + jt * 48) * 512;   // row m: j = jt*48 + m%48
  const float* vrow0 = v + (b * 192 + ip * 3) * 512;    // row m: i = ip*3 + m/48

  {  // Phase 0: E0 = relu(u[j] + v[i] + b_ca) -> bf16 LDS
    const int hc = (tid & 127) * 4, m0 = tid >> 7;
    const float4 v0 = *(const float4*)(vrow0 + hc);
    const float4 v1 = *(const float4*)(vrow0 + 512 + hc);
    const float4 v2 = *(const float4*)(vrow0 + 1024 + hc);
    const float4 bb = *(const float4*)(bca + hc);
#pragma unroll 4
    for (int m = m0; m < 144; m += 4) {
      const int ii = (m >= 96) ? 2 : (m >= 48 ? 1 : 0);
      const int jj = m - ii * 48;
      const float4 vv = (ii == 0) ? v0 : (ii == 1) ? v1 : v2;
      const float4 uu = *(const float4*)(urow0 + jj * 512 + hc);
      short4v s;
      s.x = (short)f2bf(fmaxf(uu.x + vv.x + bb.x, 0.f));
      s.y = (short)f2bf(fmaxf(uu.y + vv.y + bb.y, 0.f));
      s.z = (short)f2bf(fmaxf(uu.z + vv.z + bb.z, 0.f));
      s.w = (short)f2bf(fmaxf(uu.w + vv.w + bb.w, 0.f));
      *(short4v*)&A[m * LDSW + hc] = s;
    }
  }
  __syncthreads();

  const int nbase = wave * 64;
  f32x4 acc[9][4];

  // layer cb
  zero_acc<9, 4>(acc);
  gemm_kloop<9, 4>(A, Wcb, lane, nbase, acc);
  __syncthreads();                 // all waves done reading E0
  store_relu_lds<9, 4>(A, bcb, lane, nbase, acc);
  __syncthreads();

  // layer cc
  zero_acc<9, 4>(acc);
  gemm_kloop<9, 4>(A, Wcc, lane, nbase, acc);
  __syncthreads();
  store_relu_lds<9, 4>(A, bcc, lane, nbase, acc);
  __syncthreads();

  // final: out = E2 @ Wout^T + bout.  k-split across 8 waves, n padded 2->16.
  f32x4 oacc[9];
#pragma unroll
  for (int mt = 0; mt < 9; ++mt) { f32x4 z = {0.f, 0.f, 0.f, 0.f}; oacc[mt] = z; }
  const int n2 = lane & 15, kg2 = lane >> 4;
#pragma unroll
  for (int kk = 0; kk < 2; ++kk) {
    const int e = wave * 64 + kk * 32 + kg2 * 8;
    short8 bf = {0, 0, 0, 0, 0, 0, 0, 0};
    if (n2 < 2) bf = *(const short8*)(Wout + n2 * 512 + e);
#pragma unroll
    for (int mt = 0; mt < 9; ++mt) {
      const short8 af = *(const short8*)(A + (mt * 16 + n2) * LDSW + e);
      oacc[mt] = __builtin_amdgcn_mfma_f32_16x16x32_bf16(af, bf, oacc[mt], 0, 0, 0);
    }
  }
  if (n2 < 2) {
#pragma unroll
    for (int mt = 0; mt < 9; ++mt)
#pragma unroll
      for (int r = 0; r < 4; ++r) {
        const int row = mt * 16 + kg2 * 4 + r;
        red[(row * 2 + n2) * 8 + wave] = oacc[mt][r];
      }
  }
  __syncthreads();
  if (tid < 288) {
    const int row = tid >> 1, o = tid & 1;
    float s = bout[o];
#pragma unroll
    for (int w = 0; w < 8; ++w) s += red[(row * 2 + o) * 8 + w];
    const int ii = (row >= 96) ? 2 : (row >= 48 ? 1 : 0);
    const int jj = row - ii * 48;
    out[((b * 192 + ip * 3 + ii) * 192 + jt * 48 + jj) * 2 + o] = s;
  }
}

// ---------------- the fused cooperative kernel ----------------
__global__ __launch_bounds__(512, 2) void fused_kernel(
    const float* bv, const float* xy, const float* Wxy, const float* bxy,
    const float* ba, const float* bb, const float* bca, const float* bcb,
    const float* bcc, const float* bout,
    const float* Wa, const float* Wb, const float* Wca, const float* Wcb,
    const float* Wcc, const float* Wout,
    short* S, short* f1, short* f2, float* u, float* v, float* out) {
  __shared__ short A[144 * LDSW];      // 149,760 B (node phases use as X)
  __shared__ float red[144 * 2 * 8];   //   9,216 B (node L1 uses [0..127] as xyl)
  cg::grid_group grid = cg::this_grid();

  // ---- phase P: prep (fp32 -> bf16, dst-major tiled relayout) ----
  {
    const int gtid = blockIdx.x * 512 + threadIdx.x;
    const int stride = gridDim.x * 512;
    const int M = 262144;
    const int NV = (6 * M + 1024) / 8;
    for (int idx = gtid; idx < NV; idx += stride) {
      const int d0 = idx * 8;
      const float* src;
      if (d0 >= 6 * M) {
        src = Wout + (d0 - 6 * M);
      } else {
        const int r = d0 / M;
        if (r == 2 || r == 3) {
          const int t = d0 - 2 * M;
          const int tile = t >> 9, l = t & 511;
          const int c = (tile >> 4) * 16 + (l >> 5);   // 0..1023
          const int k = (tile & 15) * 32 + (l & 31);
          src = (c < 512) ? (Wca + c * 1024 + k) : (Wca + (c - 512) * 1024 + 512 + k);
        } else {
          const int t = d0 - r * M;
          const int tile = t >> 9, l = t & 511;
          const int c = (tile >> 4) * 16 + (l >> 5);
          const int k = (tile & 15) * 32 + (l & 31);
          const float* base = (r == 0) ? Wa : (r == 1) ? Wb : (r == 4) ? Wcb : Wcc;
          src = base + c * 512 + k;
        }
      }
      const float4 a = *(const float4*)src;
      const float4 b = *(const float4*)(src + 4);
      short8 s;
      s[0] = (short)f2bf(a.x); s[1] = (short)f2bf(a.y);
      s[2] = (short)f2bf(a.z); s[3] = (short)f2bf(a.w);
      s[4] = (short)f2bf(b.x); s[5] = (short)f2bf(b.y);
      s[6] = (short)f2bf(b.z); s[7] = (short)f2bf(b.w);
      *(short8*)(S + d0) = s;
    }
  }
  grid.sync();

  // ---- node L1: 12 rt x 4 ct = 48 blocks ----
  if (blockIdx.x < 48)
    node_phase<1>(A, red, bv, S, ba, xy, Wxy, bxy, f1, nullptr);
  grid.sync();
  // ---- node L2: 48 blocks ----
  if (blockIdx.x < 48)
    node_phase<2>(A, red, f1, S + 262144, bb, nullptr, nullptr, nullptr, f2, nullptr);
  grid.sync();
  // ---- node L3: 12 rt x 8 ct = 96 blocks ----
  if (blockIdx.x < 96)
    node_phase<3>(A, red, f2, S + 524288, nullptr, nullptr, nullptr, nullptr, u, v);
  grid.sync();

  // ---- edge: 4 tiles per block (1024 total) ----
  const short* WcbB  = S + 1048576;
  const short* WccB  = S + 1310720;
  const short* WoutB = S + 1572864;
  for (int t = 0; t < 4; ++t)
    edge_tile(A, red, t * 256 + blockIdx.x, u, v, WcbB, WccB, WoutB,
              bca, bcb, bcc, bout, out);
}

extern "C" void kernel_launch(void* const* d_in, const int* in_sizes, int n_in,
                              void* d_out, int out_size, void* d_ws, size_t ws_size,
                              hipStream_t stream) {
  const float* bv   = (const float*)d_in[0];
  const float* xy   = (const float*)d_in[1];
  const float* Wxy  = (const float*)d_in[2];
  const float* bxy  = (const float*)d_in[3];
  const float* Wa   = (const float*)d_in[4];
  const float* ba   = (const float*)d_in[5];
  const float* Wb   = (const float*)d_in[6];
  const float* bb   = (const float*)d_in[7];
  const float* Wca  = (const float*)d_in[8];
  const float* bca  = (const float*)d_in[9];
  const float* Wcb  = (const float*)d_in[10];
  const float* bcb  = (const float*)d_in[11];
  const float* Wcc  = (const float*)d_in[12];
  const float* bcc  = (const float*)d_in[13];
  const float* Wout = (const float*)d_in[14];
  const float* bout = (const float*)d_in[15];
  float* out = (float*)d_out;

  // ws layout (bytes): [0, 3,147,776) bf16 weights (tiled);
  // f1 bf16 @3,147,776 (aliased by u fp32; f1 dead before L3 writes u);
  // f2 bf16 @4,720,640; v fp32 @5,507,072; end 7,079,936.
  short* S  = (short*)d_ws;
  char* base = (char*)d_ws;
  short* f1 = (short*)(base + 3147776);
  float* u  = (float*)(base + 3147776);
  short* f2 = (short*)(base + 4720640);
  float* v  = (float*)(base + 5507072);

  void* kargs[] = {
    (void*)&bv, (void*)&xy, (void*)&Wxy, (void*)&bxy, (void*)&ba, (void*)&bb,
    (void*)&bca, (void*)&bcb, (void*)&bcc, (void*)&bout,
    (void*)&Wa, (void*)&Wb, (void*)&Wca, (void*)&Wcb, (void*)&Wcc, (void*)&Wout,
    (void*)&S, (void*)&f1, (void*)&f2, (void*)&u, (void*)&v, (void*)&out,
  };
  hipLaunchCooperativeKernel((const void*)fused_kernel, dim3(256), dim3(512),
                             kargs, 0, stream);
}